// Round 1
// baseline (1203.253 us; speedup 1.0000x reference)
//
#include <hip/hip_runtime.h>
#include <math.h>

#define Bq 64
#define Hq 256
#define Lq 1024
#define HLq (Hq*Lq)        // 262144
#define BHLq (Bq*Hq*Lq)    // 16777216
#define HNq (Hq*64)        // 16384

__device__ __forceinline__ float sigmoidf_(float x){ return 1.f/(1.f+expf(-x)); }

// ---------------- K1: time embedding + SiLU + ada linear -> scale/shift (B x 2048)
__global__ void k_ada(const int* __restrict__ tptr, const float* __restrict__ ada_w,
                      const float* __restrict__ ada_b, float* __restrict__ scsh){
  __shared__ float St[16][68];
  __shared__ float Wt[16][68];
  const int tid = threadIdx.x;
  const int o0 = blockIdx.x * 64;
  const int to = tid & 15, tb = tid >> 4;
  float acc[4][4] = {};
  const float ci = -logf(10000.f) / 511.f;
  for (int ko = 0; ko < 1024; ko += 16) {
    #pragma unroll
    for (int q = 0; q < 4; ++q) {
      int e = tid*4 + q;
      int kk = e >> 6, bb = e & 63;
      int i = ko + kk;
      float f = expf(ci * (float)(i & 511));
      float arg = (float)tptr[bb] * f;
      float val = (i < 512) ? sinf(arg) : cosf(arg);
      St[kk][bb] = val * sigmoidf_(val);
    }
    #pragma unroll
    for (int q = 0; q < 4; ++q) {
      int e = tid*4 + q;
      int oo = e >> 4, kk = e & 15;
      Wt[kk][oo] = ada_w[(size_t)(o0+oo)*1024 + ko + kk];
    }
    __syncthreads();
    #pragma unroll
    for (int kk = 0; kk < 16; ++kk) {
      float4 w = *(const float4*)&Wt[kk][to*4];
      float4 s = *(const float4*)&St[kk][tb*4];
      float wa[4] = {w.x,w.y,w.z,w.w};
      float sa[4] = {s.x,s.y,s.z,s.w};
      #pragma unroll
      for (int i=0;i<4;++i)
        #pragma unroll
        for (int j=0;j<4;++j) acc[i][j] += wa[i]*sa[j];
    }
    __syncthreads();
  }
  #pragma unroll
  for (int i=0;i<4;++i){
    int o = o0 + to*4 + i;
    float bias = ada_b[o];
    #pragma unroll
    for (int j=0;j<4;++j){
      int bb = tb*4 + j;
      scsh[bb*2048 + o] = acc[i][j] + bias;
    }
  }
}

// ---------------- K2: AdaLayerNorm over L per (b,h) row
__global__ void k_adaln(const float* __restrict__ x, const float* __restrict__ scsh,
                        float* __restrict__ A){
  const int bid = blockIdx.x;        // b*H + h
  const int b = bid >> 8;
  const int tid = threadIdx.x;
  const float4* row = (const float4*)(x + (size_t)bid*1024);
  float4 v = row[tid];
  float s = v.x+v.y+v.z+v.w;
  float ss = v.x*v.x+v.y*v.y+v.z*v.z+v.w*v.w;
  #pragma unroll
  for (int off=32; off; off>>=1){ s += __shfl_xor(s,off); ss += __shfl_xor(ss,off); }
  __shared__ float rs_[4], rss_[4];
  int lane = tid & 63, w = tid >> 6;
  if (!lane){ rs_[w]=s; rss_[w]=ss; }
  __syncthreads();
  s  = rs_[0]+rs_[1]+rs_[2]+rs_[3];
  ss = rss_[0]+rss_[1]+rss_[2]+rss_[3];
  float mean = s * (1.f/1024.f);
  float var  = ss*(1.f/1024.f) - mean*mean;
  float rstd = rsqrtf(var + 1e-5f);
  float4 sc = ((const float4*)(scsh + b*2048))[tid];
  float4 sh = ((const float4*)(scsh + b*2048 + 1024))[tid];
  float4 o;
  o.x = (v.x-mean)*rstd*(1.f+sc.x) + sh.x;
  o.y = (v.y-mean)*rstd*(1.f+sc.y) + sh.y;
  o.z = (v.z-mean)*rstd*(1.f+sc.z) + sh.z;
  o.w = (v.w-mean)*rstd*(1.f+sc.w) + sh.w;
  ((float4*)(A + (size_t)bid*1024))[tid] = o;
}

// ---------------- K3: channel LayerNorm over H per (b,l)
__global__ void k_chln(const float* __restrict__ A, const float* __restrict__ nw,
                       const float* __restrict__ nb, float* __restrict__ Z){
  const int b = blockIdx.y;
  const int l = blockIdx.x*256 + threadIdx.x;
  const float* base = A + (size_t)b*HLq + l;
  float s=0.f, ss=0.f;
  for (int h=0; h<256; ++h){ float v = base[h*1024]; s+=v; ss+=v*v; }
  float mean = s*(1.f/256.f);
  float var  = ss*(1.f/256.f) - mean*mean;
  float rstd = rsqrtf(var+1e-5f);
  float* zb = Z + (size_t)b*HLq + l;
  for (int h=0; h<256; ++h){
    float v = base[h*1024];
    zb[h*1024] = (v-mean)*rstd*nw[h] + nb[h];
  }
}

// ---------------- K4: SSM kernels K0/K1 (2,H,L) via direct Vandermonde sum
__global__ void k_ssmk(const float* __restrict__ log_dt, const float* __restrict__ A_re,
                       const float* __restrict__ A_im, const float* __restrict__ C_re,
                       const float* __restrict__ C_im, float* __restrict__ Kbuf){
  const int h = blockIdx.y;
  const int tid = threadIdx.x;
  __shared__ float dre[64], dim_[64], c0r[64], c0i[64], c1r[64], c1i[64];
  if (tid < 64){
    int n = tid;
    float dt = expf(log_dt[h]);
    float Ar = -expf(A_re[h*64+n]);
    float Ai = A_im[h*64+n];
    float dr = dt*Ar, di = dt*Ai;
    float er = expf(dr);
    float dAr = er*cosf(di), dAi = er*sinf(di);
    float den = Ar*Ar + Ai*Ai;
    float nr = dAr - 1.f, ni = dAi;
    float qr = (nr*Ar + ni*Ai)/den;
    float qi = (ni*Ar - nr*Ai)/den;
    float C0r = C_re[h*64+n],       C0i = C_im[h*64+n];
    float C1r = C_re[HNq + h*64+n], C1i = C_im[HNq + h*64+n];
    c0r[n] = C0r*qr - C0i*qi; c0i[n] = C0r*qi + C0i*qr;
    c1r[n] = C1r*qr - C1i*qi; c1i[n] = C1r*qi + C1i*qr;
    dre[n] = dr; dim_[n] = di;
  }
  __syncthreads();
  int l = blockIdx.x*256 + tid;
  float lf = (float)l;
  float a0=0.f, a1=0.f;
  for (int n=0;n<64;++n){
    float e  = expf(lf*dre[n]);
    float ph = lf*dim_[n];
    float wr = e*cosf(ph), wi = e*sinf(ph);
    a0 += c0r[n]*wr - c0i[n]*wi;
    a1 += c1r[n]*wr - c1i[n]*wi;
  }
  Kbuf[h*1024 + l]       = 2.f*a0;
  Kbuf[HLq + h*1024 + l] = 2.f*a1;
}

// ---------------- K5: bidirectional conv (Toeplitz matmul) + D*z + exact GELU
__global__ __launch_bounds__(128) void k_conv(const float* __restrict__ Z,
                       const float* __restrict__ Kbuf,
                       const float* __restrict__ Dp, float* __restrict__ C){
  const int tid = threadIdx.x;
  const int b0 = blockIdx.x * 8;
  const int h  = blockIdx.y;
  __shared__ float zs[8][1024];
  __shared__ float kf[2048];
  const float* K0 = Kbuf + h*1024;
  const float* K1 = Kbuf + HLq + h*1024;
  for (int i = tid; i < 2048; i += 128){
    int d = i - 1023;
    float v = 0.f;
    if (i < 2047) v = (d >= 0) ? K0[d] : K1[-d-1];
    kf[i] = v;
  }
  for (int r = 0; r < 8; ++r){
    const float4* zr = (const float4*)(Z + ((size_t)(b0+r)*256 + h)*1024);
    float4* dst = (float4*)zs[r];
    for (int i = tid; i < 256; i += 128) dst[i] = zr[i];
  }
  __syncthreads();
  float acc[8][8] = {};
  for (int j = 0; j < 1024; ++j){
    float kv[8], zv[8];
    #pragma unroll
    for (int mi=0;mi<8;++mi) kv[mi] = kf[1023 + tid + 128*mi - j];
    #pragma unroll
    for (int r=0;r<8;++r) zv[r] = zs[r][j];
    #pragma unroll
    for (int r=0;r<8;++r)
      #pragma unroll
      for (int mi=0;mi<8;++mi) acc[r][mi] += zv[r]*kv[mi];
  }
  float Dh = Dp[h];
  #pragma unroll
  for (int r=0;r<8;++r){
    float* crow = C + ((size_t)(b0+r)*256 + h)*1024;
    #pragma unroll
    for (int mi=0;mi<8;++mi){
      int m = tid + 128*mi;
      float v = acc[r][mi] + Dh*zs[r][m];
      crow[m] = 0.5f*v*(1.f + erff(v*0.70710678118f));
    }
  }
}

// ---------------- K6: x2 = out_w @ gelu_y + out_b + x1 ; g = tanh(x2)*sigmoid(x2)
__global__ void k_gemm_gate(const float* __restrict__ Cin, const float* __restrict__ W,
                            const float* __restrict__ bias, const float* __restrict__ A,
                            float* __restrict__ G){
  __shared__ float Wt[16][68];
  __shared__ float Ut[16][68];
  const int tid = threadIdx.x;
  const int l0 = blockIdx.x * 64;
  const int o0 = blockIdx.y * 64;
  const int b  = blockIdx.z;
  const int to = tid & 15, tb = tid >> 4;
  float acc[4][4] = {};
  for (int ko = 0; ko < 256; ko += 16){
    #pragma unroll
    for (int q=0;q<4;++q){
      int e = tid*4 + q;
      int oo = e >> 4, kk = e & 15;
      Wt[kk][oo] = W[(o0+oo)*256 + ko + kk];
    }
    {
      int kk = tid >> 4, ll = (tid & 15)*4;
      float4 u = *(const float4*)&Cin[((size_t)b*256 + ko + kk)*1024 + l0 + ll];
      *(float4*)&Ut[kk][ll] = u;
    }
    __syncthreads();
    #pragma unroll
    for (int kk=0; kk<16; ++kk){
      float4 w = *(const float4*)&Wt[kk][tb*4];
      float4 u = *(const float4*)&Ut[kk][to*4];
      float wa[4]={w.x,w.y,w.z,w.w}, ua[4]={u.x,u.y,u.z,u.w};
      #pragma unroll
      for (int i=0;i<4;++i)
        #pragma unroll
        for (int j=0;j<4;++j) acc[i][j] += wa[i]*ua[j];
    }
    __syncthreads();
  }
  #pragma unroll
  for (int i=0;i<4;++i){
    int o = o0 + tb*4 + i;
    float bo = bias[o];
    size_t idx = ((size_t)b*256 + o)*1024 + l0 + to*4;
    float4 av = *(const float4*)&A[idx];
    float aa[4] = {av.x,av.y,av.z,av.w};
    float4 g;
    float* gp = &g.x;
    #pragma unroll
    for (int j=0;j<4;++j){
      float v = acc[i][j] + bo + aa[j];
      gp[j] = tanhf(v) * sigmoidf_(v);
    }
    *(float4*)&G[idx] = g;
  }
}

// ---------------- K7: out1 = lin1@g + b1 + x1 ; out2 = lin2@g + b2
__global__ void k_gemm_out(const float* __restrict__ G, const float* __restrict__ W1,
                           const float* __restrict__ b1, const float* __restrict__ W2,
                           const float* __restrict__ b2, const float* __restrict__ A,
                           float* __restrict__ out){
  __shared__ float W1t[16][68];
  __shared__ float W2t[16][68];
  __shared__ float Ut[16][68];
  const int tid = threadIdx.x;
  const int l0 = blockIdx.x * 64;
  const int o0 = blockIdx.y * 64;
  const int b  = blockIdx.z;
  const int to = tid & 15, tb = tid >> 4;
  float acc1[4][4] = {};
  float acc2[4][4] = {};
  for (int ko = 0; ko < 256; ko += 16){
    #pragma unroll
    for (int q=0;q<4;++q){
      int e = tid*4 + q;
      int oo = e >> 4, kk = e & 15;
      W1t[kk][oo] = W1[(o0+oo)*256 + ko + kk];
      W2t[kk][oo] = W2[(o0+oo)*256 + ko + kk];
    }
    {
      int kk = tid >> 4, ll = (tid & 15)*4;
      float4 u = *(const float4*)&G[((size_t)b*256 + ko + kk)*1024 + l0 + ll];
      *(float4*)&Ut[kk][ll] = u;
    }
    __syncthreads();
    #pragma unroll
    for (int kk=0; kk<16; ++kk){
      float4 w1 = *(const float4*)&W1t[kk][tb*4];
      float4 w2 = *(const float4*)&W2t[kk][tb*4];
      float4 u  = *(const float4*)&Ut[kk][to*4];
      float wa1[4]={w1.x,w1.y,w1.z,w1.w}, wa2[4]={w2.x,w2.y,w2.z,w2.w}, ua[4]={u.x,u.y,u.z,u.w};
      #pragma unroll
      for (int i=0;i<4;++i)
        #pragma unroll
        for (int j=0;j<4;++j){ acc1[i][j] += wa1[i]*ua[j]; acc2[i][j] += wa2[i]*ua[j]; }
    }
    __syncthreads();
  }
  #pragma unroll
  for (int i=0;i<4;++i){
    int o = o0 + tb*4 + i;
    float bo1 = b1[o], bo2 = b2[o];
    size_t idx = ((size_t)b*256 + o)*1024 + l0 + to*4;
    float4 av = *(const float4*)&A[idx];
    float aa[4] = {av.x,av.y,av.z,av.w};
    float4 o1, o2;
    float* p1 = &o1.x; float* p2 = &o2.x;
    #pragma unroll
    for (int j=0;j<4;++j){
      p1[j] = acc1[i][j] + bo1 + aa[j];
      p2[j] = acc2[i][j] + bo2;
    }
    *(float4*)&out[idx] = o1;
    *(float4*)&out[BHLq + idx] = o2;
  }
}

extern "C" void kernel_launch(void* const* d_in, const int* in_sizes, int n_in,
                              void* d_out, int out_size, void* d_ws, size_t ws_size,
                              hipStream_t stream){
  const float* x      = (const float*)d_in[0];
  const int*   t      = (const int*)  d_in[1];
  const float* ada_w  = (const float*)d_in[2];
  const float* ada_b  = (const float*)d_in[3];
  const float* norm_w = (const float*)d_in[4];
  const float* norm_b = (const float*)d_in[5];
  const float* log_dt = (const float*)d_in[6];
  const float* A_re   = (const float*)d_in[7];
  const float* A_im   = (const float*)d_in[8];
  const float* C_re   = (const float*)d_in[9];
  const float* C_im   = (const float*)d_in[10];
  const float* Dp     = (const float*)d_in[11];
  const float* out_w  = (const float*)d_in[12];
  const float* out_b  = (const float*)d_in[13];
  const float* lin1_w = (const float*)d_in[14];
  const float* lin1_b = (const float*)d_in[15];
  const float* lin2_w = (const float*)d_in[16];
  const float* lin2_b = (const float*)d_in[17];

  float* A    = (float*)d_ws;        // x1 (AdaLN out), BHL floats
  float* Z    = A + BHLq;            // z, later reused as g, BHL floats
  float* Kbuf = Z + BHLq;            // 2*H*L floats
  float* scsh = Kbuf + 2*HLq;        // B*2048 floats
  float* C    = (float*)d_out;       // gelu(y) scratch in d_out first half
  float* out  = (float*)d_out;

  k_ada   <<<32, 256, 0, stream>>>(t, ada_w, ada_b, scsh);
  k_adaln <<<Bq*Hq, 256, 0, stream>>>(x, scsh, A);
  k_chln  <<<dim3(4, Bq), 256, 0, stream>>>(A, norm_w, norm_b, Z);
  k_ssmk  <<<dim3(4, Hq), 256, 0, stream>>>(log_dt, A_re, A_im, C_re, C_im, Kbuf);
  k_conv  <<<dim3(8, Hq), 128, 0, stream>>>(Z, Kbuf, Dp, C);
  k_gemm_gate<<<dim3(16, 4, Bq), 256, 0, stream>>>(C, out_w, out_b, A, Z);
  k_gemm_out <<<dim3(16, 4, Bq), 256, 0, stream>>>(Z, lin1_w, lin1_b, lin2_w, lin2_b, A, out);
}

// Round 2
// 627.250 us; speedup vs baseline: 1.9183x; 1.9183x over previous
//
#include <hip/hip_runtime.h>
#include <math.h>

#define Bq 64
#define Hq 256
#define Lq 1024
#define HLq (Hq*Lq)        // 262144
#define BHLq (Bq*Hq*Lq)    // 16777216
#define HNq (Hq*64)        // 16384

typedef __attribute__((ext_vector_type(8))) short bf16x8;
typedef __attribute__((ext_vector_type(4))) float f32x4;

__device__ __forceinline__ float sigmoidf_(float x){ return 1.f/(1.f+expf(-x)); }
__device__ __forceinline__ unsigned short f2bf(float f){
  unsigned u = __float_as_uint(f);
  u += 0x7FFF + ((u>>16)&1);
  return (unsigned short)(u>>16);
}
__device__ __forceinline__ float bf2f(unsigned short h){ return __uint_as_float(((unsigned)h)<<16); }

// ---------------- K1: time embedding + SiLU + ada linear -> scale/shift (B x 2048)
__global__ void k_ada(const int* __restrict__ tptr, const float* __restrict__ ada_w,
                      const float* __restrict__ ada_b, float* __restrict__ scsh){
  __shared__ float St[16][68];
  __shared__ float Wt[16][68];
  const int tid = threadIdx.x;
  const int o0 = blockIdx.x * 64;
  const int to = tid & 15, tb = tid >> 4;
  float acc[4][4] = {};
  const float ci = -logf(10000.f) / 511.f;
  for (int ko = 0; ko < 1024; ko += 16) {
    #pragma unroll
    for (int q = 0; q < 4; ++q) {
      int e = tid*4 + q;
      int kk = e >> 6, bb = e & 63;
      int i = ko + kk;
      float f = expf(ci * (float)(i & 511));
      float arg = (float)tptr[bb] * f;
      float val = (i < 512) ? sinf(arg) : cosf(arg);
      St[kk][bb] = val * sigmoidf_(val);
    }
    #pragma unroll
    for (int q = 0; q < 4; ++q) {
      int e = tid*4 + q;
      int oo = e >> 4, kk = e & 15;
      Wt[kk][oo] = ada_w[(size_t)(o0+oo)*1024 + ko + kk];
    }
    __syncthreads();
    #pragma unroll
    for (int kk = 0; kk < 16; ++kk) {
      float4 w = *(const float4*)&Wt[kk][to*4];
      float4 s = *(const float4*)&St[kk][tb*4];
      float wa[4] = {w.x,w.y,w.z,w.w};
      float sa[4] = {s.x,s.y,s.z,s.w};
      #pragma unroll
      for (int i=0;i<4;++i)
        #pragma unroll
        for (int j=0;j<4;++j) acc[i][j] += wa[i]*sa[j];
    }
    __syncthreads();
  }
  #pragma unroll
  for (int i=0;i<4;++i){
    int o = o0 + to*4 + i;
    float bias = ada_b[o];
    #pragma unroll
    for (int j=0;j<4;++j){
      int bb = tb*4 + j;
      scsh[bb*2048 + o] = acc[i][j] + bias;
    }
  }
}

// ---------------- K2: AdaLayerNorm over L per (b,h) row -> Ax (fp32)
__global__ void k_adaln(const float* __restrict__ x, const float* __restrict__ scsh,
                        float* __restrict__ A){
  const int bid = blockIdx.x;        // b*H + h
  const int b = bid >> 8;
  const int tid = threadIdx.x;
  const float4* row = (const float4*)(x + (size_t)bid*1024);
  float4 v = row[tid];
  float s = v.x+v.y+v.z+v.w;
  float ss = v.x*v.x+v.y*v.y+v.z*v.z+v.w*v.w;
  #pragma unroll
  for (int off=32; off; off>>=1){ s += __shfl_xor(s,off); ss += __shfl_xor(ss,off); }
  __shared__ float rs_[4], rss_[4];
  int lane = tid & 63, w = tid >> 6;
  if (!lane){ rs_[w]=s; rss_[w]=ss; }
  __syncthreads();
  s  = rs_[0]+rs_[1]+rs_[2]+rs_[3];
  ss = rss_[0]+rss_[1]+rss_[2]+rss_[3];
  float mean = s * (1.f/1024.f);
  float var  = ss*(1.f/1024.f) - mean*mean;
  float rstd = rsqrtf(var + 1e-5f);
  float4 sc = ((const float4*)(scsh + b*2048))[tid];
  float4 sh = ((const float4*)(scsh + b*2048 + 1024))[tid];
  float4 o;
  o.x = (v.x-mean)*rstd*(1.f+sc.x) + sh.x;
  o.y = (v.y-mean)*rstd*(1.f+sc.y) + sh.y;
  o.z = (v.z-mean)*rstd*(1.f+sc.z) + sh.z;
  o.w = (v.w-mean)*rstd*(1.f+sc.w) + sh.w;
  ((float4*)(A + (size_t)bid*1024))[tid] = o;
}

// ---------------- K3: channel LayerNorm over H per (b,l) -> z in bf16
__global__ void k_chln(const float* __restrict__ A, const float* __restrict__ nw,
                       const float* __restrict__ nb, unsigned short* __restrict__ Zb){
  const int b = blockIdx.y;
  const int l = blockIdx.x*256 + threadIdx.x;
  const float* base = A + (size_t)b*HLq + l;
  float s=0.f, ss=0.f;
  for (int h=0; h<256; ++h){ float v = base[h*1024]; s+=v; ss+=v*v; }
  float mean = s*(1.f/256.f);
  float var  = ss*(1.f/256.f) - mean*mean;
  float rstd = rsqrtf(var+1e-5f);
  unsigned short* zb = Zb + (size_t)b*HLq + l;
  for (int h=0; h<256; ++h){
    float v = base[h*1024];
    zb[h*1024] = f2bf((v-mean)*rstd*nw[h] + nb[h]);
  }
}

// ---------------- K4: SSM kernels K0/K1 (2,H,L) via direct Vandermonde sum (fp32)
__global__ void k_ssmk(const float* __restrict__ log_dt, const float* __restrict__ A_re,
                       const float* __restrict__ A_im, const float* __restrict__ C_re,
                       const float* __restrict__ C_im, float* __restrict__ Kbuf){
  const int h = blockIdx.y;
  const int tid = threadIdx.x;
  __shared__ float dre[64], dim_[64], c0r[64], c0i[64], c1r[64], c1i[64];
  if (tid < 64){
    int n = tid;
    float dt = expf(log_dt[h]);
    float Ar = -expf(A_re[h*64+n]);
    float Ai = A_im[h*64+n];
    float dr = dt*Ar, di = dt*Ai;
    float er = expf(dr);
    float dAr = er*cosf(di), dAi = er*sinf(di);
    float den = Ar*Ar + Ai*Ai;
    float nr = dAr - 1.f, ni = dAi;
    float qr = (nr*Ar + ni*Ai)/den;
    float qi = (ni*Ar - nr*Ai)/den;
    float C0r = C_re[h*64+n],       C0i = C_im[h*64+n];
    float C1r = C_re[HNq + h*64+n], C1i = C_im[HNq + h*64+n];
    c0r[n] = C0r*qr - C0i*qi; c0i[n] = C0r*qi + C0i*qr;
    c1r[n] = C1r*qr - C1i*qi; c1i[n] = C1r*qi + C1i*qr;
    dre[n] = dr; dim_[n] = di;
  }
  __syncthreads();
  int l = blockIdx.x*256 + tid;
  float lf = (float)l;
  float a0=0.f, a1=0.f;
  for (int n=0;n<64;++n){
    float e  = expf(lf*dre[n]);
    float ph = lf*dim_[n];
    float wr = e*cosf(ph), wi = e*sinf(ph);
    a0 += c0r[n]*wr - c0i[n]*wi;
    a1 += c1r[n]*wr - c1i[n]*wi;
  }
  Kbuf[h*1024 + l]       = 2.f*a0;
  Kbuf[HLq + h*1024 + l] = 2.f*a1;
}

// ---------------- K5: bidirectional Toeplitz conv via bf16 MFMA + D*z + GELU -> Cb bf16
// Per block: h fixed, M=64 batches, N=512 outputs, K=1024.
// B operand read straight from 8 shifted copies of the reversed kernel vector.
__global__ __launch_bounds__(256,2) void k_conv(const unsigned short* __restrict__ Zb,
        const float* __restrict__ Kbuf, const float* __restrict__ Dp,
        unsigned short* __restrict__ Cb){
  __shared__ unsigned short kcopy[8][2056];   // stride 2056 el = 1028 dw = 4 mod 32 (bank spread)
  __shared__ unsigned short As[64][136];      // z tile, Kc=128, +8 pad
  const int tid = threadIdx.x;
  const int h  = blockIdx.y;
  const int l0 = blockIdx.x * 512;
  const float* K0 = Kbuf + h*1024;
  const float* K1 = Kbuf + HLq + h*1024;
  // krev[p] = kf[2046-p]; kf[1023+d] = d>=0 ? K0[d] : K1[-d-1]; copy[s][i] = krev[i+s]
  for (int idx = tid; idx < 8*2056; idx += 256){
    int s = idx / 2056;
    int i = idx - s*2056;
    int q = 2046 - i - s;
    float v = 0.f;
    if (q >= 0) v = (q >= 1023) ? K0[q-1023] : K1[1022-q];
    kcopy[s][i] = f2bf(v);
  }
  const int lane = tid & 63;
  const int w    = tid >> 6;
  const int ln   = lane & 15;
  const int quad = lane >> 4;
  int kofs[8];
  #pragma unroll
  for (int nt=0; nt<8; ++nt){
    int l = l0 + w*128 + nt*16 + ln;
    int d = 1023 - l;              // krev base = d + j
    int s = d & 7;
    kofs[nt] = s*2056 + (d - s) + quad*8;   // 16B-aligned element offset
  }
  const unsigned short* kbase = &kcopy[0][0];
  f32x4 acc[4][8] = {};
  for (int c = 0; c < 8; ++c){
    __syncthreads();
    #pragma unroll
    for (int pass = 0; pass < 4; ++pass){
      int b = pass*16 + (tid>>4);
      int col = (tid & 15)*8;
      *(uint4*)&As[b][col] = *(const uint4*)(Zb + ((size_t)b*256 + h)*1024 + c*128 + col);
    }
    __syncthreads();
    #pragma unroll
    for (int ks = 0; ks < 4; ++ks){
      int kk = ks*32 + quad*8;
      bf16x8 af[4];
      #pragma unroll
      for (int mt=0; mt<4; ++mt) af[mt] = *(const bf16x8*)&As[mt*16+ln][kk];
      int jb = c*128 + ks*32;
      bf16x8 bv[8];
      #pragma unroll
      for (int nt=0; nt<8; ++nt) bv[nt] = *(const bf16x8*)(kbase + kofs[nt] + jb);
      #pragma unroll
      for (int mt=0; mt<4; ++mt)
        #pragma unroll
        for (int nt=0; nt<8; ++nt)
          acc[mt][nt] = __builtin_amdgcn_mfma_f32_16x16x32_bf16(af[mt], bv[nt], acc[mt][nt], 0,0,0);
    }
  }
  float Dh = Dp[h];
  #pragma unroll
  for (int mt=0; mt<4; ++mt){
    #pragma unroll
    for (int reg=0; reg<4; ++reg){
      int b = mt*16 + quad*4 + reg;
      const unsigned short* zrow = Zb + ((size_t)b*256+h)*1024;
      unsigned short* crow = Cb + ((size_t)b*256+h)*1024;
      #pragma unroll
      for (int nt=0; nt<8; ++nt){
        int l = l0 + w*128 + nt*16 + ln;
        float y = acc[mt][nt][reg] + Dh*bf2f(zrow[l]);
        float g = 0.5f*y*(1.f + erff(y*0.70710678118f));
        crow[l] = f2bf(g);
      }
    }
  }
}

// ---------------- K6: x2 = out_w @ u + out_b + x1 ; g = tanh(x2)*sigmoid(x2)  (bf16 MFMA)
__global__ __launch_bounds__(256,2) void k_gate(const unsigned short* __restrict__ U,
        const float* __restrict__ W, const float* __restrict__ bias,
        const float* __restrict__ Ax, unsigned short* __restrict__ G){
  __shared__ unsigned short Ws[64][72];
  __shared__ unsigned short Us[256][72];
  const int tid = threadIdx.x;
  const int l0 = blockIdx.x * 256;
  const int o0 = blockIdx.y * 64;
  const int b  = blockIdx.z;
  const int lane = tid & 63, w = tid>>6, ln = lane&15, quad = lane>>4;
  f32x4 acc[4][4] = {};
  for (int ch = 0; ch < 4; ++ch){
    int ic0 = ch*64;
    __syncthreads();
    { // Ws: 64 o x 64 i (fp32 -> bf16)
      int o = tid & 63;
      int i = (tid >> 6) * 16;
      const float* wsrc = W + (size_t)(o0+o)*256 + ic0 + i;
      unsigned pk[8];
      #pragma unroll
      for (int r=0;r<8;++r) pk[r] = (unsigned)f2bf(wsrc[2*r]) | ((unsigned)f2bf(wsrc[2*r+1])<<16);
      uint4* dst = (uint4*)&Ws[o][i];
      dst[0] = make_uint4(pk[0],pk[1],pk[2],pk[3]);
      dst[1] = make_uint4(pk[4],pk[5],pk[6],pk[7]);
    }
    // Us: [l][i] = U[b][ic0+i][l0+l]  (transpose staging, 4 i per 8B write)
    #pragma unroll
    for (int it = 0; it < 16; ++it){
      int i4 = (tid>>6) + 4*(it&3);
      int l  = (it>>2)*64 + (tid&63);
      const unsigned short* usrc = U + ((size_t)b*256 + ic0 + i4*4)*1024 + l0 + l;
      unsigned short e0 = usrc[0], e1 = usrc[1024], e2 = usrc[2048], e3 = usrc[3072];
      uint2 val; val.x = (unsigned)e0 | ((unsigned)e1<<16); val.y = (unsigned)e2 | ((unsigned)e3<<16);
      *(uint2*)&Us[l][i4*4] = val;
    }
    __syncthreads();
    #pragma unroll
    for (int ks = 0; ks < 2; ++ks){
      int kk = ks*32 + quad*8;
      bf16x8 af[4], bv[4];
      #pragma unroll
      for (int mt=0;mt<4;++mt) af[mt] = *(const bf16x8*)&Ws[mt*16+ln][kk];
      #pragma unroll
      for (int nt=0;nt<4;++nt) bv[nt] = *(const bf16x8*)&Us[w*64+nt*16+ln][kk];
      #pragma unroll
      for (int mt=0;mt<4;++mt)
        #pragma unroll
        for (int nt=0;nt<4;++nt)
          acc[mt][nt] = __builtin_amdgcn_mfma_f32_16x16x32_bf16(af[mt], bv[nt], acc[mt][nt],0,0,0);
    }
  }
  #pragma unroll
  for (int mt=0;mt<4;++mt){
    #pragma unroll
    for (int reg=0;reg<4;++reg){
      int o = o0 + mt*16 + quad*4 + reg;
      float bo = bias[o];
      const float* arow = Ax + ((size_t)b*256 + o)*1024;
      unsigned short* grow = G + ((size_t)b*256 + o)*1024;
      #pragma unroll
      for (int nt=0;nt<4;++nt){
        int l = l0 + w*64 + nt*16 + ln;
        float v = acc[mt][nt][reg] + bo + arow[l];
        float g = tanhf(v)*sigmoidf_(v);
        grow[l] = f2bf(g);
      }
    }
  }
}

// ---------------- K7: out1 = lin1@g + b1 + x1 ; out2 = lin2@g + b2  (bf16 MFMA, dual acc)
__global__ __launch_bounds__(256,2) void k_out(const unsigned short* __restrict__ G,
        const float* __restrict__ W1, const float* __restrict__ b1,
        const float* __restrict__ W2, const float* __restrict__ b2,
        const float* __restrict__ Ax, float* __restrict__ out){
  __shared__ unsigned short W1s[64][72];
  __shared__ unsigned short W2s[64][72];
  __shared__ unsigned short Us[256][72];
  const int tid = threadIdx.x;
  const int l0 = blockIdx.x * 256;
  const int o0 = blockIdx.y * 64;
  const int b  = blockIdx.z;
  const int lane = tid & 63, w = tid>>6, ln = lane&15, quad = lane>>4;
  f32x4 acc1[4][4] = {};
  f32x4 acc2[4][4] = {};
  for (int ch = 0; ch < 4; ++ch){
    int ic0 = ch*64;
    __syncthreads();
    {
      int o = tid & 63;
      int i = (tid >> 6) * 16;
      const float* w1src = W1 + (size_t)(o0+o)*256 + ic0 + i;
      const float* w2src = W2 + (size_t)(o0+o)*256 + ic0 + i;
      unsigned pk[8];
      #pragma unroll
      for (int r=0;r<8;++r) pk[r] = (unsigned)f2bf(w1src[2*r]) | ((unsigned)f2bf(w1src[2*r+1])<<16);
      uint4* dst1 = (uint4*)&W1s[o][i];
      dst1[0] = make_uint4(pk[0],pk[1],pk[2],pk[3]);
      dst1[1] = make_uint4(pk[4],pk[5],pk[6],pk[7]);
      #pragma unroll
      for (int r=0;r<8;++r) pk[r] = (unsigned)f2bf(w2src[2*r]) | ((unsigned)f2bf(w2src[2*r+1])<<16);
      uint4* dst2 = (uint4*)&W2s[o][i];
      dst2[0] = make_uint4(pk[0],pk[1],pk[2],pk[3]);
      dst2[1] = make_uint4(pk[4],pk[5],pk[6],pk[7]);
    }
    #pragma unroll
    for (int it = 0; it < 16; ++it){
      int i4 = (tid>>6) + 4*(it&3);
      int l  = (it>>2)*64 + (tid&63);
      const unsigned short* usrc = G + ((size_t)b*256 + ic0 + i4*4)*1024 + l0 + l;
      unsigned short e0 = usrc[0], e1 = usrc[1024], e2 = usrc[2048], e3 = usrc[3072];
      uint2 val; val.x = (unsigned)e0 | ((unsigned)e1<<16); val.y = (unsigned)e2 | ((unsigned)e3<<16);
      *(uint2*)&Us[l][i4*4] = val;
    }
    __syncthreads();
    #pragma unroll
    for (int ks = 0; ks < 2; ++ks){
      int kk = ks*32 + quad*8;
      bf16x8 bv[4];
      #pragma unroll
      for (int nt=0;nt<4;++nt) bv[nt] = *(const bf16x8*)&Us[w*64+nt*16+ln][kk];
      #pragma unroll
      for (int mt=0;mt<4;++mt){
        bf16x8 a1 = *(const bf16x8*)&W1s[mt*16+ln][kk];
        #pragma unroll
        for (int nt=0;nt<4;++nt)
          acc1[mt][nt] = __builtin_amdgcn_mfma_f32_16x16x32_bf16(a1, bv[nt], acc1[mt][nt],0,0,0);
      }
      #pragma unroll
      for (int mt=0;mt<4;++mt){
        bf16x8 a2 = *(const bf16x8*)&W2s[mt*16+ln][kk];
        #pragma unroll
        for (int nt=0;nt<4;++nt)
          acc2[mt][nt] = __builtin_amdgcn_mfma_f32_16x16x32_bf16(a2, bv[nt], acc2[mt][nt],0,0,0);
      }
    }
  }
  #pragma unroll
  for (int mt=0;mt<4;++mt){
    #pragma unroll
    for (int reg=0;reg<4;++reg){
      int o = o0 + mt*16 + quad*4 + reg;
      float bo1 = b1[o], bo2 = b2[o];
      const float* arow = Ax + ((size_t)b*256 + o)*1024;
      float* o1row = out + ((size_t)b*256 + o)*1024;
      float* o2row = o1row + BHLq;
      #pragma unroll
      for (int nt=0;nt<4;++nt){
        int l = l0 + w*64 + nt*16 + ln;
        o1row[l] = acc1[mt][nt][reg] + bo1 + arow[l];
        o2row[l] = acc2[mt][nt][reg] + bo2;
      }
    }
  }
}

extern "C" void kernel_launch(void* const* d_in, const int* in_sizes, int n_in,
                              void* d_out, int out_size, void* d_ws, size_t ws_size,
                              hipStream_t stream){
  const float* x      = (const float*)d_in[0];
  const int*   t      = (const int*)  d_in[1];
  const float* ada_w  = (const float*)d_in[2];
  const float* ada_b  = (const float*)d_in[3];
  const float* norm_w = (const float*)d_in[4];
  const float* norm_b = (const float*)d_in[5];
  const float* log_dt = (const float*)d_in[6];
  const float* A_re   = (const float*)d_in[7];
  const float* A_im   = (const float*)d_in[8];
  const float* C_re   = (const float*)d_in[9];
  const float* C_im   = (const float*)d_in[10];
  const float* Dp     = (const float*)d_in[11];
  const float* out_w  = (const float*)d_in[12];
  const float* out_b  = (const float*)d_in[13];
  const float* lin1_w = (const float*)d_in[14];
  const float* lin1_b = (const float*)d_in[15];
  const float* lin2_w = (const float*)d_in[16];
  const float* lin2_b = (const float*)d_in[17];

  float* Ax            = (float*)d_ws;                     // x1 fp32, BHL
  unsigned short* Zb   = (unsigned short*)(Ax + BHLq);     // z bf16, BHL
  unsigned short* Cb   = Zb + BHLq;                        // gelu(y) bf16, BHL
  float* Kbuf          = (float*)(Cb + BHLq);              // 2*H*L fp32
  float* scsh          = Kbuf + 2*HLq;                     // B*2048 fp32
  unsigned short* Gb   = Zb;                               // gate g bf16 aliases dead z
  float* out           = (float*)d_out;

  k_ada   <<<32, 256, 0, stream>>>(t, ada_w, ada_b, scsh);
  k_adaln <<<Bq*Hq, 256, 0, stream>>>(x, scsh, Ax);
  k_chln  <<<dim3(4, Bq), 256, 0, stream>>>(Ax, norm_w, norm_b, Zb);
  k_ssmk  <<<dim3(4, Hq), 256, 0, stream>>>(log_dt, A_re, A_im, C_re, C_im, Kbuf);
  k_conv  <<<dim3(2, Hq), 256, 0, stream>>>(Zb, Kbuf, Dp, Cb);
  k_gate  <<<dim3(4, 4, Bq), 256, 0, stream>>>(Cb, out_w, out_b, Ax, Gb);
  k_out   <<<dim3(4, 4, Bq), 256, 0, stream>>>(Gb, lin1_w, lin1_b, lin2_w, lin2_b, Ax, out);
}